// Round 3
// baseline (180.520 us; speedup 1.0000x reference)
//
#include <hip/hip_runtime.h>
#include <stdint.h>

// ---------------------------------------------------------------------------
// TopK: scores = (embs @ scorer)/sum(scorer) + mask; top-k rows; out = rows^T
// ORDERING must match the harness's numpy fp32 reference. numpy dispatches
// (100000,256)@(256,1) f32 to OpenBLAS sgemv_t (GEMM->GEMV forward), whose
// Haswell/Zen microkernel computes each dot as 8 mod-8 fp32 fma chains
// (lane j sums elements j, j+8, ..., j+248 sequentially) reduced as
//   dot = ((L0+L4)+(L1+L5)) + ((L2+L6)+(L3+L7)).
// We emulate those bits exactly; /S is monotone so its bits don't matter.
// Keys are 32-bit order-preserving maps of the fp32 score; ties -> lower idx
// (matches jax.lax.top_k / stable argsort).
// ws budget ~73KB; the 400KB key array lives in d_out (overwritten by k5).
// ---------------------------------------------------------------------------

#define NBINS 8192   // 13-bit radix: sign + exp(8) + mantissa(4)
#define BIN_SHIFT 19
#define CAP 4096     // candidates: k + boundary bin (~400) << CAP

__device__ __forceinline__ uint32_t f2key(float f) {
  uint32_t b = __float_as_uint(f);
  return (b & 0x80000000u) ? ~b : (b | 0x80000000u);
}

// ---- kernel 0: zero hist + counters, S = (float)sum_f64(scorer) -----------
__global__ __launch_bounds__(256) void k0_init(
    const float* __restrict__ scorer, int F,
    uint32_t* __restrict__ hdr, uint32_t* __restrict__ hist) {
  int gid = blockIdx.x * 256 + threadIdx.x;
  if (gid < NBINS) hist[gid] = 0;
  if (blockIdx.x == 0 && threadIdx.x < 64) {
    double s = 0.0;
    for (int j = threadIdx.x; j < F; j += 64) s += (double)scorer[j];
#pragma unroll
    for (int off = 32; off >= 1; off >>= 1) s += __shfl_xor(s, off, 64);
    if (threadIdx.x == 0) {
      hdr[0] = 0;                  // bucket B
      hdr[1] = 0;                  // count strictly above B
      hdr[2] = 0;                  // candidate counter
      ((float*)hdr)[4] = (float)s; // S (byte offset 16)
    }
  }
}

// ---- kernel 1: one THREAD per row; OpenBLAS-sgemv_t-ordered fp32 dot ------
// Block = 256 threads = 256 rows. Embeddings staged through LDS in 32-col
// chunks (pitch 33 -> 2-way bank aliasing only, which is free).
__global__ __launch_bounds__(256) void k1_scores(
    const float* __restrict__ embs, const float* __restrict__ mask,
    const float* __restrict__ scorer, const uint32_t* __restrict__ hdr,
    uint32_t* __restrict__ keys, uint32_t* __restrict__ hist, int N) {
  __shared__ float tile[256 * 33];
  __shared__ float sw[256];
  int t = threadIdx.x;
  int r0 = blockIdx.x * 256;
  float S = ((const float*)hdr)[4];
  sw[t] = scorer[t];  // F == 256
  float L[8];
#pragma unroll
  for (int j = 0; j < 8; ++j) L[j] = 0.f;
  const float4* e4 = (const float4*)embs;
  for (int ch = 0; ch < 8; ++ch) {
    int c04 = ch * 8;  // chunk start in float4 units (32 floats)
    __syncthreads();   // tile reuse + (ch==0) sw visibility
#pragma unroll
    for (int m = 0; m < 8; ++m) {
      int flat = m * 256 + t;  // 0..2047 = 256 rows x 8 float4
      int rr = flat >> 3;
      int cc4 = flat & 7;
      int row = r0 + rr;
      float4 v = make_float4(0.f, 0.f, 0.f, 0.f);
      if (row < N) v = e4[(size_t)row * 64 + c04 + cc4];
      float* dst = &tile[rr * 33 + cc4 * 4];
      dst[0] = v.x; dst[1] = v.y; dst[2] = v.z; dst[3] = v.w;
    }
    __syncthreads();
#pragma unroll
    for (int c = 0; c < 32; ++c) {  // ascending k within each mod-8 lane
      float a = tile[t * 33 + c];
      float w = sw[ch * 32 + c];
      L[c & 7] = fmaf(a, w, L[c & 7]);
    }
  }
  int row = r0 + t;
  if (row < N) {
    // OpenBLAS haswell sgemv_t horizontal reduce:
    // vextractf128+vaddps (lo+hi), then vhaddps x2
    float m0 = L[0] + L[4];
    float m1 = L[1] + L[5];
    float m2 = L[2] + L[6];
    float m3 = L[3] + L[7];
    float dot = (m0 + m1) + (m2 + m3);
    float score = dot / S + mask[row];  // IEEE fp32 div (default hipcc)
    uint32_t key = f2key(score);
    keys[row] = key;
    atomicAdd(&hist[key >> BIN_SHIFT], 1u);
  }
}

// ---- kernel 2: suffix-scan 8192-bin histogram, find k-th bucket -----------
__global__ __launch_bounds__(1024) void k2_findbucket(
    const uint32_t* __restrict__ hist, uint32_t* __restrict__ hdr, int k) {
  __shared__ uint32_t part[1024];
  __shared__ uint32_t scan[1024];
  int t = threadIdx.x;
  const uint4* h4 = (const uint4*)hist;  // 8 bins per thread
  uint4 a = h4[t * 2];
  uint4 b = h4[t * 2 + 1];
  uint32_t p = a.x + a.y + a.z + a.w + b.x + b.y + b.z + b.w;
  part[t] = p;
  scan[t] = p;
  __syncthreads();
  for (int off = 1; off < 1024; off <<= 1) {
    uint32_t v = (t + off < 1024) ? scan[t + off] : 0u;
    __syncthreads();
    scan[t] += v;
    __syncthreads();
  }
  uint32_t above = scan[t] - part[t];  // count with bin >= (t+1)*8
  if (above < (uint32_t)k && above + part[t] >= (uint32_t)k) {
    uint32_t cum = above;
    for (int bn = t * 8 + 7; bn >= t * 8; --bn) {
      uint32_t h = hist[bn];
      if (cum + h >= (uint32_t)k) { hdr[0] = (uint32_t)bn; hdr[1] = cum; break; }
      cum += h;
    }
  }
}

// ---- kernel 3: compact candidates (bin >= B), block-aggregated atomic ------
__global__ __launch_bounds__(256) void k3_compact(
    const uint32_t* __restrict__ keys, const uint32_t* __restrict__ hdr,
    uint32_t* __restrict__ ckey, uint32_t* __restrict__ cidx,
    uint32_t* __restrict__ counter, int N) {
  __shared__ uint32_t wcnt[4];
  __shared__ uint32_t wbase[4];
  __shared__ uint32_t blkbase;
  int i = blockIdx.x * 256 + threadIdx.x;
  int wave = threadIdx.x >> 6, lane = threadIdx.x & 63;
  uint32_t B = hdr[0];
  bool pred = false;
  uint32_t key = 0;
  if (i < N) {
    key = keys[i];
    pred = (key >> BIN_SHIFT) >= B;
  }
  unsigned long long ball = __ballot(pred);
  uint32_t prefix = (uint32_t)__popcll(ball & ((1ull << lane) - 1ull));
  if (lane == 0) wcnt[wave] = (uint32_t)__popcll(ball);
  __syncthreads();
  if (threadIdx.x == 0) {
    uint32_t tot = wcnt[0] + wcnt[1] + wcnt[2] + wcnt[3];
    blkbase = tot ? atomicAdd(counter, tot) : 0u;
    wbase[0] = 0;
    wbase[1] = wcnt[0];
    wbase[2] = wcnt[0] + wcnt[1];
    wbase[3] = wcnt[0] + wcnt[1] + wcnt[2];
  }
  __syncthreads();
  if (pred) {
    uint32_t pos = blkbase + wbase[wave] + prefix;
    if (pos < CAP) { ckey[pos] = key; cidx[pos] = (uint32_t)i; }
  }
}

// ---- kernel 4: exact rank (key desc, idx asc); scatter index by rank -------
__global__ __launch_bounds__(256) void k4_rank(
    const uint32_t* __restrict__ ckey, const uint32_t* __restrict__ cidx,
    const uint32_t* __restrict__ hdr, uint32_t* __restrict__ oidx, int k) {
  __shared__ uint32_t lk[CAP];
  __shared__ uint32_t li[CAP];
  uint32_t C = hdr[2];
  if (C > CAP) C = CAP;
  uint32_t base = blockIdx.x * 256u;
  if (base >= C) return;
  for (uint32_t j = threadIdx.x; j < C; j += 256u) {
    lk[j] = ckey[j];
    li[j] = cidx[j];
  }
  __syncthreads();
  uint32_t gid = base + threadIdx.x;
  if (gid >= C) return;
  uint32_t mk = lk[gid];
  uint32_t mi = li[gid];
  uint32_t cnt = 0;
  for (uint32_t j = 0; j < C; ++j) {
    uint32_t kj = lk[j];
    cnt += (kj > mk || (kj == mk && li[j] < mi)) ? 1u : 0u;
  }
  if (cnt < (uint32_t)k) oidx[cnt] = mi;
}

// ---- kernel 5: gather selected rows, transpose via padded LDS tile ---------
__global__ __launch_bounds__(256) void k5_gather(
    const float* __restrict__ embs, const uint32_t* __restrict__ oidx,
    float* __restrict__ out, int k) {
  __shared__ float lds[256 * 33];  // [feat][rank], pitch 33
  __shared__ uint32_t sidx[32];
  int r0 = blockIdx.x * 32;
  int t = threadIdx.x;
  if (t < 32 && r0 + t < k) sidx[t] = oidx[r0 + t];
  __syncthreads();
  int nvalid = min(32, k - r0);
  for (int rr = 0; rr < nvalid; ++rr) {
    lds[t * 33 + rr] = embs[(size_t)sidx[rr] * 256 + t];  // 1KB coalesced/row
  }
  __syncthreads();
  int rl = t & 31;
  int fbase = t >> 5;  // 0..7
  if (r0 + rl < k) {
#pragma unroll
    for (int i = 0; i < 32; ++i) {
      int f = i * 8 + fbase;
      out[(size_t)f * k + r0 + rl] = lds[f * 33 + rl];  // 128B segments
    }
  }
}

extern "C" void kernel_launch(void* const* d_in, const int* in_sizes, int n_in,
                              void* d_out, int out_size, void* d_ws, size_t ws_size,
                              hipStream_t stream) {
  const float* embs = (const float*)d_in[0];
  const float* mask = (const float*)d_in[1];
  const float* scorer = (const float*)d_in[2];
  int F = in_sizes[2];      // 256
  int N = in_sizes[0] / F;  // 100000
  int k = out_size / F;     // 2000

  // keys live in d_out (N*4 = 400KB << 2MB); k5 overwrites all of d_out.
  uint32_t* keys = (uint32_t*)d_out;

  char* ws = (char*)d_ws;
  uint32_t* hdr = (uint32_t*)ws;                         // 1KB
  uint32_t* hist = (uint32_t*)(ws + 1024);               // 32KB
  uint32_t* ckey = (uint32_t*)(ws + 1024 + NBINS * 4);   // 16KB
  uint32_t* cidx = ckey + CAP;                           // 16KB
  uint32_t* oidx = cidx + CAP;                           // 8KB

  k0_init<<<NBINS / 256, 256, 0, stream>>>(scorer, F, hdr, hist);
  k1_scores<<<(N + 255) / 256, 256, 0, stream>>>(embs, mask, scorer, hdr, keys, hist, N);
  k2_findbucket<<<1, 1024, 0, stream>>>(hist, hdr, k);
  k3_compact<<<(N + 255) / 256, 256, 0, stream>>>(keys, hdr, ckey, cidx, &hdr[2], N);
  k4_rank<<<CAP / 256, 256, 0, stream>>>(ckey, cidx, hdr, oidx, k);
  k5_gather<<<(k + 31) / 32, 256, 0, stream>>>(embs, oidx, (float*)d_out, k);
}

// Round 5
// 179.990 us; speedup vs baseline: 1.0029x; 1.0029x over previous
//
#include <hip/hip_runtime.h>
#include <stdint.h>

// ---------------------------------------------------------------------------
// TopK: scores = (embs @ scorer)/sum(scorer) + mask; top-k rows; out = rows^T
// Ordering matches numpy/OpenBLAS sgemv_t fp32 bits exactly (verified R3,
// absmax=0): per row, 8 mod-8 fma chains (chain c sums elements c, c+8, ...
// ascending), reduced as ((L0+L4)+(L1+L5)) + ((L2+L6)+(L3+L7)).
// 8 threads per row own 1 chain each; shfl_xor pair-sums preserve the exact
// bracket (IEEE add is bitwise-commutative).
// R5 fix: k1 staging loop must fill 32 rows x 32 float4 = 1024 f4 -> m=0..3
// (R4 ran m=0..1, leaving rows 16..31 uninitialized -> garbage scores).
// ---------------------------------------------------------------------------

#define NBINS 8192   // 13-bit radix: sign + exp(8) + mantissa(4)
#define BIN_SHIFT 19
#define CAP 4096     // candidates: k + boundary bin << CAP

__device__ __forceinline__ uint32_t f2key(float f) {
  uint32_t b = __float_as_uint(f);
  return (b & 0x80000000u) ? ~b : (b | 0x80000000u);
}

// ---- kernel 0: zero hist + counters, S = (float)sum_f64(scorer) -----------
__global__ __launch_bounds__(256) void k0_init(
    const float* __restrict__ scorer, int F,
    uint32_t* __restrict__ hdr, uint32_t* __restrict__ hist) {
  int gid = blockIdx.x * 256 + threadIdx.x;
  if (gid < NBINS) hist[gid] = 0;
  if (blockIdx.x == 0 && threadIdx.x < 64) {
    double s = 0.0;
    for (int j = threadIdx.x; j < F; j += 64) s += (double)scorer[j];
#pragma unroll
    for (int off = 32; off >= 1; off >>= 1) s += __shfl_xor(s, off, 64);
    if (threadIdx.x == 0) {
      hdr[0] = 0;                  // bucket B
      hdr[1] = 0;                  // count strictly above B
      hdr[2] = 0;                  // candidate counter
      ((float*)hdr)[4] = (float)s; // S (byte offset 16)
    }
  }
}

// ---- kernel 1: 32 rows/block, 8 threads/row (one mod-8 chain each) --------
// Two 128-col chunks staged in LDS (pitch 132 -> <=2-way bank alias = free).
__global__ __launch_bounds__(256) void k1_scores(
    const float* __restrict__ embs, const float* __restrict__ mask,
    const float* __restrict__ scorer, const uint32_t* __restrict__ hdr,
    uint32_t* __restrict__ keys, uint32_t* __restrict__ hist, int N) {
  __shared__ float tile[32 * 132];
  __shared__ float sw[256];
  int t = threadIdx.x;
  int r0 = blockIdx.x * 32;
  float S = ((const float*)hdr)[4];
  sw[t] = scorer[t];  // F == 256
  int r = t >> 3, c = t & 7;
  float acc = 0.f;
  const float4* e4 = (const float4*)embs;
#pragma unroll
  for (int ch = 0; ch < 2; ++ch) {
    if (ch) __syncthreads();  // previous chunk's reads complete
#pragma unroll
    for (int m = 0; m < 4; ++m) {      // 4*256 = 1024 f4 = 32 rows x 32 f4
      int flat = m * 256 + t;
      int rr = flat >> 5;              // 0..31
      int cc4 = flat & 31;             // 0..31
      int row = r0 + rr;
      float4 v = make_float4(0.f, 0.f, 0.f, 0.f);
      if (row < N) v = e4[(size_t)row * 64 + ch * 32 + cc4];  // 512B/row segs
      float* dst = &tile[rr * 132 + cc4 * 4];
      dst[0] = v.x; dst[1] = v.y; dst[2] = v.z; dst[3] = v.w;
    }
    __syncthreads();
#pragma unroll
    for (int sl = 0; sl < 16; ++sl) {  // ascending k within the chain
      acc = fmaf(tile[r * 132 + c + 8 * sl], sw[ch * 128 + c + 8 * sl], acc);
    }
  }
  // exact OpenBLAS bracket via commutative pair-sums:
  float m1 = acc + __shfl_xor(acc, 4, 64);  // m_{c&3} = L_c + L_{c+4}
  float p1 = m1 + __shfl_xor(m1, 1, 64);    // (m0+m1) / (m2+m3)
  float dot = p1 + __shfl_xor(p1, 2, 64);   // ((m0+m1)+(m2+m3))
  int row = r0 + r;
  if (c == 0 && row < N) {
    float score = dot / S + mask[row];
    uint32_t key = f2key(score);
    keys[row] = key;
    atomicAdd(&hist[key >> BIN_SHIFT], 1u);
  }
}

// ---- kernel 2: suffix-scan 8192-bin histogram, find k-th bucket -----------
__global__ __launch_bounds__(1024) void k2_findbucket(
    const uint32_t* __restrict__ hist, uint32_t* __restrict__ hdr, int k) {
  __shared__ uint32_t part[1024];
  __shared__ uint32_t scan[1024];
  int t = threadIdx.x;
  const uint4* h4 = (const uint4*)hist;  // 8 bins per thread
  uint4 a = h4[t * 2];
  uint4 b = h4[t * 2 + 1];
  uint32_t p = a.x + a.y + a.z + a.w + b.x + b.y + b.z + b.w;
  part[t] = p;
  scan[t] = p;
  __syncthreads();
  for (int off = 1; off < 1024; off <<= 1) {
    uint32_t v = (t + off < 1024) ? scan[t + off] : 0u;
    __syncthreads();
    scan[t] += v;
    __syncthreads();
  }
  uint32_t above = scan[t] - part[t];  // count with bin >= (t+1)*8
  if (above < (uint32_t)k && above + part[t] >= (uint32_t)k) {
    uint32_t cum = above;
    for (int bn = t * 8 + 7; bn >= t * 8; --bn) {
      uint32_t h = hist[bn];
      if (cum + h >= (uint32_t)k) { hdr[0] = (uint32_t)bn; hdr[1] = cum; break; }
      cum += h;
    }
  }
}

// ---- kernel 3: compact candidates (bin >= B), block-aggregated atomic ------
__global__ __launch_bounds__(256) void k3_compact(
    const uint32_t* __restrict__ keys, const uint32_t* __restrict__ hdr,
    uint32_t* __restrict__ ckey, uint32_t* __restrict__ cidx,
    uint32_t* __restrict__ counter, int N) {
  __shared__ uint32_t wcnt[4];
  __shared__ uint32_t wbase[4];
  __shared__ uint32_t blkbase;
  int i = blockIdx.x * 256 + threadIdx.x;
  int wave = threadIdx.x >> 6, lane = threadIdx.x & 63;
  uint32_t B = hdr[0];
  bool pred = false;
  uint32_t key = 0;
  if (i < N) {
    key = keys[i];
    pred = (key >> BIN_SHIFT) >= B;
  }
  unsigned long long ball = __ballot(pred);
  uint32_t prefix = (uint32_t)__popcll(ball & ((1ull << lane) - 1ull));
  if (lane == 0) wcnt[wave] = (uint32_t)__popcll(ball);
  __syncthreads();
  if (threadIdx.x == 0) {
    uint32_t tot = wcnt[0] + wcnt[1] + wcnt[2] + wcnt[3];
    blkbase = tot ? atomicAdd(counter, tot) : 0u;
    wbase[0] = 0;
    wbase[1] = wcnt[0];
    wbase[2] = wcnt[0] + wcnt[1];
    wbase[3] = wcnt[0] + wcnt[1] + wcnt[2];
  }
  __syncthreads();
  if (pred) {
    uint32_t pos = blkbase + wbase[wave] + prefix;
    if (pos < CAP) { ckey[pos] = key; cidx[pos] = (uint32_t)i; }
  }
}

// ---- kernel 4: wave-per-candidate exact rank (key desc, idx asc) -----------
__global__ __launch_bounds__(256) void k4_rank(
    const uint32_t* __restrict__ ckey, const uint32_t* __restrict__ cidx,
    const uint32_t* __restrict__ hdr, uint32_t* __restrict__ oidx, int k) {
  __shared__ uint32_t lk[CAP];
  __shared__ uint32_t li[CAP];
  uint32_t C = hdr[2];
  if (C > CAP) C = CAP;
  uint32_t base = blockIdx.x * 4u;  // 4 candidates per block (1 per wave)
  if (base >= C) return;
  for (uint32_t j = threadIdx.x; j < C; j += 256u) {
    lk[j] = ckey[j];
    li[j] = cidx[j];
  }
  __syncthreads();
  int wave = threadIdx.x >> 6, lane = threadIdx.x & 63;
  uint32_t gid = base + wave;
  if (gid >= C) return;
  uint32_t mk = lk[gid];
  uint32_t mi = li[gid];
  uint32_t cnt = 0;
  for (uint32_t j = lane; j < C; j += 64u) {  // ~C/64 iters per lane
    uint32_t kj = lk[j];
    cnt += (kj > mk || (kj == mk && li[j] < mi)) ? 1u : 0u;
  }
#pragma unroll
  for (int off = 32; off >= 1; off >>= 1) cnt += __shfl_xor(cnt, off, 64);
  if (lane == 0 && cnt < (uint32_t)k) oidx[cnt] = mi;
}

// ---- kernel 5: gather + transpose; 16 ranks x 128 feats per block ----------
__global__ __launch_bounds__(256) void k5_gather(
    const float* __restrict__ embs, const uint32_t* __restrict__ oidx,
    float* __restrict__ out, int k) {
  __shared__ float tile[16 * 132];
  __shared__ uint32_t sidx[16];
  int t = threadIdx.x;
  int r0 = blockIdx.x * 16;
  int fb = blockIdx.y * 128;
  if (t < 16) sidx[t] = (r0 + t < k) ? oidx[r0 + t] : 0u;
  __syncthreads();
  const float4* e4 = (const float4*)embs;
#pragma unroll
  for (int m = 0; m < 2; ++m) {      // 2*256 = 512 f4 = 16 rows x 32 f4
    int flat = m * 256 + t;
    int rr = flat >> 5;
    int cc4 = flat & 31;
    float4 v = e4[(size_t)sidx[rr] * 64 + (fb >> 2) + cc4];
    float* dst = &tile[rr * 132 + cc4 * 4];
    dst[0] = v.x; dst[1] = v.y; dst[2] = v.z; dst[3] = v.w;
  }
  __syncthreads();
  int fl = t >> 1;   // 0..127 local feature
  int rq = t & 1;    // which 8-rank group
  float v[8];
#pragma unroll
  for (int i = 0; i < 8; ++i) v[i] = tile[(rq * 8 + i) * 132 + fl];
  size_t obase = (size_t)(fb + fl) * k + r0 + rq * 8;
  if (((k & 3) == 0) && (r0 + rq * 8 + 7 < k)) {
    *(float4*)(out + obase) = make_float4(v[0], v[1], v[2], v[3]);
    *(float4*)(out + obase + 4) = make_float4(v[4], v[5], v[6], v[7]);
  } else {
#pragma unroll
    for (int i = 0; i < 8; ++i)
      if (r0 + rq * 8 + i < k) out[obase + i] = v[i];
  }
}

extern "C" void kernel_launch(void* const* d_in, const int* in_sizes, int n_in,
                              void* d_out, int out_size, void* d_ws, size_t ws_size,
                              hipStream_t stream) {
  const float* embs = (const float*)d_in[0];
  const float* mask = (const float*)d_in[1];
  const float* scorer = (const float*)d_in[2];
  int F = in_sizes[2];      // 256
  int N = in_sizes[0] / F;  // 100000
  int k = out_size / F;     // 2000

  // keys live in d_out (N*4 = 400KB << 2MB); k5 overwrites all of d_out.
  uint32_t* keys = (uint32_t*)d_out;

  char* ws = (char*)d_ws;
  uint32_t* hdr = (uint32_t*)ws;                         // 1KB
  uint32_t* hist = (uint32_t*)(ws + 1024);               // 32KB
  uint32_t* ckey = (uint32_t*)(ws + 1024 + NBINS * 4);   // 16KB
  uint32_t* cidx = ckey + CAP;                           // 16KB
  uint32_t* oidx = cidx + CAP;                           // 8KB

  k0_init<<<NBINS / 256, 256, 0, stream>>>(scorer, F, hdr, hist);
  k1_scores<<<(N + 31) / 32, 256, 0, stream>>>(embs, mask, scorer, hdr, keys, hist, N);
  k2_findbucket<<<1, 1024, 0, stream>>>(hist, hdr, k);
  k3_compact<<<(N + 255) / 256, 256, 0, stream>>>(keys, hdr, ckey, cidx, &hdr[2], N);
  k4_rank<<<CAP / 4, 256, 0, stream>>>(ckey, cidx, hdr, oidx, k);
  k5_gather<<<dim3((k + 15) / 16, 2), 256, 0, stream>>>(embs, oidx, (float*)d_out, k);
}

// Round 6
// 65.555 us; speedup vs baseline: 2.7537x; 2.7456x over previous
//
#include <hip/hip_runtime.h>
#include <stdint.h>

// ---------------------------------------------------------------------------
// TopK: scores = (embs @ scorer)/sum(scorer) + mask; top-k rows; out = rows^T
// Ordering matches numpy/OpenBLAS sgemv_t fp32 bits exactly (verified R3/R5,
// absmax=0): per row, 8 mod-8 fma chains (chain c sums elements c, c+8, ...
// ascending), reduced as ((L0+L4)+(L1+L5)) + ((L2+L6)+(L3+L7)).
// R6: global-atomic histogram removed (R5 evidence: ~330 GB/s ceiling
// independent of occupancy = hot-bin device-scope atomic serialization).
//   k1 : thread-per-row scoring, no atomics, no main-loop barriers.
//   k1b: LDS-privatized histogram, 8 partial hists stored to d_out's
//        free upper half (no global atomics).
//   k2 : reduce partials + suffix-scan + bucket walk.
// d_out layout during pipeline: keys @ [0, N*4) ; partials @ [1.024MB, +256KB).
// k5 overwrites all of d_out at the end. ws use: 41KB (hdr/ckey/cidx/oidx).
// ---------------------------------------------------------------------------

#define NBINS 8192   // 13-bit radix: sign + exp(8) + mantissa(4)
#define BIN_SHIFT 19
#define CAP 4096     // candidates: k + boundary bin (~500) << CAP
#define HPARTS 8

__device__ __forceinline__ uint32_t f2key(float f) {
  uint32_t b = __float_as_uint(f);
  return (b & 0x80000000u) ? ~b : (b | 0x80000000u);
}

// ---- kernel 1: thread-per-row fp32 dot in OpenBLAS sgemv_t order ----------
// Each thread streams its own 1KB row (64 float4, sequential -> full line
// use via L2). No atomics, no barriers after the scorer preload.
__global__ __launch_bounds__(256) void k1_scores(
    const float* __restrict__ embs, const float* __restrict__ mask,
    const float* __restrict__ scorer,
    uint32_t* __restrict__ keys, int N) {
  __shared__ float sw[256];
  __shared__ float Ssh;
  int t = threadIdx.x;
  sw[t] = scorer[t];  // F == 256
  __syncthreads();
  if (t < 64) {
    double s = 0.0;
    for (int j = t; j < 256; j += 64) s += (double)sw[j];
#pragma unroll
    for (int off = 32; off >= 1; off >>= 1) s += __shfl_xor(s, off, 64);
    if (t == 0) Ssh = (float)s;  // f64 sum: order-independent at f32 grain
  }
  __syncthreads();
  float S = Ssh;
  int row = blockIdx.x * 256 + t;
  if (row >= N) return;
  const float4* e4 = (const float4*)embs + (size_t)row * 64;
  const float4* w4 = (const float4*)sw;
  float L[8];
#pragma unroll
  for (int i = 0; i < 8; ++i) L[i] = 0.f;
#pragma unroll 16
  for (int j = 0; j < 64; ++j) {
    float4 v = e4[j];
    float4 w = w4[j];           // LDS broadcast (all lanes same addr)
    // element 4j+i belongs to chain 4*(j&1)+i; j ascending = k ascending
    if ((j & 1) == 0) {
      L[0] = fmaf(v.x, w.x, L[0]);
      L[1] = fmaf(v.y, w.y, L[1]);
      L[2] = fmaf(v.z, w.z, L[2]);
      L[3] = fmaf(v.w, w.w, L[3]);
    } else {
      L[4] = fmaf(v.x, w.x, L[4]);
      L[5] = fmaf(v.y, w.y, L[5]);
      L[6] = fmaf(v.z, w.z, L[6]);
      L[7] = fmaf(v.w, w.w, L[7]);
    }
  }
  float m0 = L[0] + L[4];
  float m1 = L[1] + L[5];
  float m2 = L[2] + L[6];
  float m3 = L[3] + L[7];
  float dot = (m0 + m1) + (m2 + m3);
  float score = dot / S + mask[row];
  keys[row] = f2key(score);
}

// ---- kernel 1b: LDS-privatized histogram -> HPARTS partial hists ----------
// 2 sub-hists per block halve same-address LDS-atomic serialization.
// Zero GLOBAL atomics. Also zeroes the k3 compact counter.
__global__ __launch_bounds__(256) void k1b_hist(
    const uint32_t* __restrict__ keys, uint32_t* __restrict__ partials,
    uint32_t* __restrict__ hdr, int N) {
  __shared__ uint32_t h[2][NBINS];  // 64 KB
  int t = threadIdx.x, b = blockIdx.x;
  for (int i = t; i < 2 * NBINS; i += 256) ((uint32_t*)h)[i] = 0u;
  if (b == 0 && t == 0) hdr[2] = 0;  // compact counter (k3 runs later)
  __syncthreads();
  int per = (N + HPARTS - 1) / HPARTS;
  int lo = b * per;
  int hi = lo + per; if (hi > N) hi = N;
  int sub = (t >> 7) & 1;
  for (int i = lo + t; i < hi; i += 256)
    atomicAdd(&h[sub][keys[i] >> BIN_SHIFT], 1u);
  __syncthreads();
  uint32_t* dst = partials + (size_t)b * NBINS;
  for (int i = t; i < NBINS; i += 256) dst[i] = h[0][i] + h[1][i];
}

// ---- kernel 2: reduce partials, suffix-scan, find k-th bucket -------------
__global__ __launch_bounds__(1024) void k2_findbucket(
    const uint32_t* __restrict__ partials, uint32_t* __restrict__ hdr, int k) {
  __shared__ uint32_t part[1024];
  __shared__ uint32_t scan[1024];
  int t = threadIdx.x;
  uint32_t rb[8];
#pragma unroll
  for (int j = 0; j < 8; ++j) rb[j] = 0u;
#pragma unroll
  for (int p = 0; p < HPARTS; ++p) {
    const uint4* q = (const uint4*)(partials + (size_t)p * NBINS) + t * 2;
    uint4 a = q[0], b2 = q[1];
    rb[0] += a.x;  rb[1] += a.y;  rb[2] += a.z;  rb[3] += a.w;
    rb[4] += b2.x; rb[5] += b2.y; rb[6] += b2.z; rb[7] += b2.w;
  }
  uint32_t p8 = rb[0] + rb[1] + rb[2] + rb[3] + rb[4] + rb[5] + rb[6] + rb[7];
  part[t] = p8;
  scan[t] = p8;
  __syncthreads();
  for (int off = 1; off < 1024; off <<= 1) {
    uint32_t v = (t + off < 1024) ? scan[t + off] : 0u;
    __syncthreads();
    scan[t] += v;
    __syncthreads();
  }
  uint32_t above = scan[t] - part[t];  // count with bin >= (t+1)*8
  if (above < (uint32_t)k && above + part[t] >= (uint32_t)k) {
    uint32_t cum = above;
    for (int jj = 7; jj >= 0; --jj) {
      if (cum + rb[jj] >= (uint32_t)k) { hdr[0] = (uint32_t)(t * 8 + jj); hdr[1] = cum; break; }
      cum += rb[jj];
    }
  }
}

// ---- kernel 3: compact candidates (bin >= B), block-aggregated atomic ------
__global__ __launch_bounds__(256) void k3_compact(
    const uint32_t* __restrict__ keys, const uint32_t* __restrict__ hdr,
    uint32_t* __restrict__ ckey, uint32_t* __restrict__ cidx,
    uint32_t* __restrict__ counter, int N) {
  __shared__ uint32_t wcnt[4];
  __shared__ uint32_t wbase[4];
  __shared__ uint32_t blkbase;
  int i = blockIdx.x * 256 + threadIdx.x;
  int wave = threadIdx.x >> 6, lane = threadIdx.x & 63;
  uint32_t B = hdr[0];
  bool pred = false;
  uint32_t key = 0;
  if (i < N) {
    key = keys[i];
    pred = (key >> BIN_SHIFT) >= B;
  }
  unsigned long long ball = __ballot(pred);
  uint32_t prefix = (uint32_t)__popcll(ball & ((1ull << lane) - 1ull));
  if (lane == 0) wcnt[wave] = (uint32_t)__popcll(ball);
  __syncthreads();
  if (threadIdx.x == 0) {
    uint32_t tot = wcnt[0] + wcnt[1] + wcnt[2] + wcnt[3];
    blkbase = tot ? atomicAdd(counter, tot) : 0u;
    wbase[0] = 0;
    wbase[1] = wcnt[0];
    wbase[2] = wcnt[0] + wcnt[1];
    wbase[3] = wcnt[0] + wcnt[1] + wcnt[2];
  }
  __syncthreads();
  if (pred) {
    uint32_t pos = blkbase + wbase[wave] + prefix;
    if (pos < CAP) { ckey[pos] = key; cidx[pos] = (uint32_t)i; }
  }
}

// ---- kernel 4: exact rank, 4 candidates/wave, 16/block --------------------
__global__ __launch_bounds__(256) void k4_rank(
    const uint32_t* __restrict__ ckey, const uint32_t* __restrict__ cidx,
    const uint32_t* __restrict__ hdr, uint32_t* __restrict__ oidx, int k) {
  __shared__ uint32_t lk[CAP];
  __shared__ uint32_t li[CAP];
  uint32_t C = hdr[2];
  if (C > CAP) C = CAP;
  uint32_t base = blockIdx.x * 16u;
  if (base >= C) return;
  for (uint32_t j = threadIdx.x; j < C; j += 256u) {
    lk[j] = ckey[j];
    li[j] = cidx[j];
  }
  __syncthreads();
  int wave = threadIdx.x >> 6, lane = threadIdx.x & 63;
  uint32_t g0 = base + wave * 4u;
  uint32_t mk[4], mi[4], cnt[4];
#pragma unroll
  for (int q = 0; q < 4; ++q) {
    uint32_t g = g0 + q;
    bool valid = g < C;
    mk[q] = valid ? lk[g] : 0u;
    mi[q] = valid ? li[g] : 0xFFFFFFFFu;
    cnt[q] = 0u;
  }
  for (uint32_t j = lane; j < C; j += 64u) {
    uint32_t kj = lk[j], ij = li[j];
#pragma unroll
    for (int q = 0; q < 4; ++q)
      cnt[q] += (kj > mk[q] || (kj == mk[q] && ij < mi[q])) ? 1u : 0u;
  }
#pragma unroll
  for (int q = 0; q < 4; ++q) {
#pragma unroll
    for (int off = 32; off >= 1; off >>= 1) cnt[q] += __shfl_xor(cnt[q], off, 64);
  }
  if (lane == 0) {
#pragma unroll
    for (int q = 0; q < 4; ++q) {
      uint32_t g = g0 + q;
      if (g < C && cnt[q] < (uint32_t)k) oidx[cnt[q]] = mi[q];
    }
  }
}

// ---- kernel 5: gather + transpose; 16 ranks x 128 feats per block ----------
__global__ __launch_bounds__(256) void k5_gather(
    const float* __restrict__ embs, const uint32_t* __restrict__ oidx,
    float* __restrict__ out, int k) {
  __shared__ float tile[16 * 132];
  __shared__ uint32_t sidx[16];
  int t = threadIdx.x;
  int r0 = blockIdx.x * 16;
  int fb = blockIdx.y * 128;
  if (t < 16) sidx[t] = (r0 + t < k) ? oidx[r0 + t] : 0u;
  __syncthreads();
  const float4* e4 = (const float4*)embs;
#pragma unroll
  for (int m = 0; m < 2; ++m) {      // 2*256 = 512 f4 = 16 rows x 32 f4
    int flat = m * 256 + t;
    int rr = flat >> 5;
    int cc4 = flat & 31;
    float4 v = e4[(size_t)sidx[rr] * 64 + (fb >> 2) + cc4];
    float* dst = &tile[rr * 132 + cc4 * 4];
    dst[0] = v.x; dst[1] = v.y; dst[2] = v.z; dst[3] = v.w;
  }
  __syncthreads();
  int fl = t >> 1;   // 0..127 local feature
  int rq = t & 1;    // which 8-rank group
  float v[8];
#pragma unroll
  for (int i = 0; i < 8; ++i) v[i] = tile[(rq * 8 + i) * 132 + fl];
  size_t obase = (size_t)(fb + fl) * k + r0 + rq * 8;
  if (((k & 3) == 0) && (r0 + rq * 8 + 7 < k)) {
    *(float4*)(out + obase) = make_float4(v[0], v[1], v[2], v[3]);
    *(float4*)(out + obase + 4) = make_float4(v[4], v[5], v[6], v[7]);
  } else {
#pragma unroll
    for (int i = 0; i < 8; ++i)
      if (r0 + rq * 8 + i < k) out[obase + i] = v[i];
  }
}

extern "C" void kernel_launch(void* const* d_in, const int* in_sizes, int n_in,
                              void* d_out, int out_size, void* d_ws, size_t ws_size,
                              hipStream_t stream) {
  const float* embs = (const float*)d_in[0];
  const float* mask = (const float*)d_in[1];
  const float* scorer = (const float*)d_in[2];
  int F = in_sizes[2];      // 256
  int N = in_sizes[0] / F;  // 100000
  int k = out_size / F;     // 2000

  // d_out scratch layout (overwritten by k5 at the end):
  //   keys     @ [0, N*4)           = 400 KB
  //   partials @ [out_size/2 * 4)   = 1.024 MB .. +256 KB
  uint32_t* keys = (uint32_t*)d_out;
  uint32_t* partials = (uint32_t*)d_out + (out_size / 2);

  char* ws = (char*)d_ws;
  uint32_t* hdr = (uint32_t*)ws;                 // 1KB: [0]=B [1]=cumAbove [2]=counter
  uint32_t* ckey = (uint32_t*)(ws + 1024);       // 16KB
  uint32_t* cidx = ckey + CAP;                   // 16KB
  uint32_t* oidx = cidx + CAP;                   // 8KB

  k1_scores<<<(N + 255) / 256, 256, 0, stream>>>(embs, mask, scorer, keys, N);
  k1b_hist<<<HPARTS, 256, 0, stream>>>(keys, partials, hdr, N);
  k2_findbucket<<<1, 1024, 0, stream>>>(partials, hdr, k);
  k3_compact<<<(N + 255) / 256, 256, 0, stream>>>(keys, hdr, ckey, cidx, &hdr[2], N);
  k4_rank<<<(CAP + 15) / 16, 256, 0, stream>>>(ckey, cidx, hdr, oidx, k);
  k5_gather<<<dim3((k + 15) / 16, 2), 256, 0, stream>>>(embs, oidx, (float*)d_out, k);
}